// Round 5
// baseline (207.551 us; speedup 1.0000x reference)
//
#include <hip/hip_runtime.h>
#include <hip/hip_bf16.h>

// Problem: N=8192 tokens, K=4096 quant dim, D=1024 out dim.
// out[n, d] = W[d, argmax_k x[n, k]]   (first-occurrence tie-break)
//
// R1: column gather of row-major W amplified HBM fetch 16x -> transpose W
//     into d_ws (R2), FETCH 465->~145 MiB.
// R4: ILP + nontemporal streams.  Main kernel still only ~2.9 TB/s.
// R5: wave-per-row restructure: 16 outstanding f4 loads per lane (4x the
//     in-flight bytes/CU), zero LDS / zero __syncthreads, in-wave shuffle
//     argmax, 4-f4/lane gather+store. Removes the per-block sync tail that
//     limited the block-per-row version.

constexpr int N = 8192;
constexpr int K = 4096;
constexpr int D = 1024;

typedef float vf4 __attribute__((ext_vector_type(4))); // clang-native float4

// ---------------- Transpose W (D x K, row-major) -> Wt (K x D) ----------------
constexpr int TILE = 64;

__global__ __launch_bounds__(256) void transpose_W(
    const float* __restrict__ W, float* __restrict__ Wt)
{
    __shared__ float tile[TILE][TILE + 1];

    const int k0 = blockIdx.x * TILE;
    const int d0 = blockIdx.y * TILE;
    const int tx = threadIdx.x % 16;
    const int ty = threadIdx.x / 16;

    #pragma unroll
    for (int p = 0; p < 4; ++p) {
        const int r = p * 16 + ty; // d_local
        const vf4 v = *(const vf4*)(W + (size_t)(d0 + r) * K + k0 + tx * 4);
        tile[r][tx * 4 + 0] = v.x;
        tile[r][tx * 4 + 1] = v.y;
        tile[r][tx * 4 + 2] = v.z;
        tile[r][tx * 4 + 3] = v.w;
    }
    __syncthreads();
    #pragma unroll
    for (int p = 0; p < 4; ++p) {
        const int r = p * 16 + ty; // k_local
        vf4 o;
        o.x = tile[tx * 4 + 0][r];
        o.y = tile[tx * 4 + 1][r];
        o.z = tile[tx * 4 + 2][r];
        o.w = tile[tx * 4 + 3][r];
        *(vf4*)(Wt + (size_t)(k0 + r) * D + d0 + tx * 4) = o;
    }
}

// ---------------- wave-per-row argmax + gather ----------------
// Block = 256 threads = 4 waves; each wave owns one row n. Grid = N/4.
__global__ __launch_bounds__(256) void steq_argmax_gather(
    const float* __restrict__ x,
    const float* __restrict__ Wt,
    float* __restrict__ out)
{
    const int t = threadIdx.x;
    const int lane = t & 63;
    const int wave = t >> 6;
    const int n = blockIdx.x * 4 + wave;

    const vf4* xv = (const vf4*)(x + (size_t)n * K);

    // 16 independent 16B nontemporal loads per lane: 1 KiB coalesced per
    // instruction across the wave, 16 deep in the vmem queue.
    vf4 v[16];
    #pragma unroll
    for (int j = 0; j < 16; ++j)
        v[j] = __builtin_nontemporal_load(&xv[j * 64 + lane]);

    float best = -__builtin_inff();
    int bidx = 0;
    // Per lane, element index (j*64+lane)*4+c increases with j and c:
    // strict '>' keeps the first occurrence within the lane.
    #pragma unroll
    for (int j = 0; j < 16; ++j) {
        const int base = (j * 64 + lane) * 4;
        if (v[j].x > best) { best = v[j].x; bidx = base + 0; }
        if (v[j].y > best) { best = v[j].y; bidx = base + 1; }
        if (v[j].z > best) { best = v[j].z; bidx = base + 2; }
        if (v[j].w > best) { best = v[j].w; bidx = base + 3; }
    }

    // In-wave reduction (64 lanes), min-index tie-break.
    #pragma unroll
    for (int off = 32; off > 0; off >>= 1) {
        const float ov = __shfl_down(best, off, 64);
        const int   oi = __shfl_down(bidx, off, 64);
        if (ov > best || (ov == best && oi < bidx)) { best = ov; bidx = oi; }
    }
    const int k = __shfl(bidx, 0, 64); // broadcast winner from lane 0

    // Gather Wt[k, :] (contiguous 4 KiB) and store out[n, :]: 4 f4 per lane.
    const vf4* wrow = (const vf4*)(Wt + (size_t)k * D);
    vf4* orow = (vf4*)(out + (size_t)n * D);
    vf4 g[4];
    #pragma unroll
    for (int j = 0; j < 4; ++j) g[j] = wrow[j * 64 + lane];
    #pragma unroll
    for (int j = 0; j < 4; ++j)
        __builtin_nontemporal_store(g[j], &orow[j * 64 + lane]);
}

extern "C" void kernel_launch(void* const* d_in, const int* in_sizes, int n_in,
                              void* d_out, int out_size, void* d_ws, size_t ws_size,
                              hipStream_t stream) {
    const float* x = (const float*)d_in[0];
    const float* W = (const float*)d_in[1];
    float* out = (float*)d_out;
    float* Wt  = (float*)d_ws; // K*D*4 = 16 MiB scratch

    dim3 tgrid(K / TILE, D / TILE); // (64, 16)
    transpose_W<<<tgrid, 256, 0, stream>>>(W, Wt);
    steq_argmax_gather<<<N / 4, 256, 0, stream>>>(x, Wt, out);
}